// Round 7
// baseline (232.455 us; speedup 1.0000x reference)
//
#include <hip/hip_runtime.h>
#include <hip/hip_bf16.h>
#include <math.h>

// Problem constants
#define NBH 32     // B*KVH = 4*8
#define HPKN 4
#define DN 128
#define SEQKV 4096
#define SEQN 4097
#define SSTR 4100  // padded score-row stride (keeps float4 alignment per row)
#define RANKN 32
#define KSEL 516   // K + SINK = 512 + 4
#define SINKN 4
#define LOCALK 128 // masked-local region starts at SEQKV - LOCALK = 3968
#define NMASK 132  // SINKN + LOCALK
#define NTOP 384   // KSEL - NMASK
#define NCHUNK 16  // k2 position-chunks per bh

// ---------------------------------------------------------------------------
// Kernel 2: per block, recompute rank-32 dim selection + scales from q via
// shuffle reductions, then approximate scores over this block's 256-position
// chunk. Emits per-chunk softmax partials (max, sum-exp) per (bh,p).
// Block x==0 writes the current-token (s=4096) score; block x==1 zeroes the
// out rows for this bh (k7 accumulates into out with atomics).
// grid (16, 32 bh), block 256.
// ---------------------------------------------------------------------------
__global__ __launch_bounds__(256) void k2_scores(
    const float* __restrict__ q, const float* __restrict__ key,
    const float* __restrict__ skey, const float* __restrict__ lm,
    float* __restrict__ scores, float* __restrict__ tk,
    float2* __restrict__ partials, float* __restrict__ out) {
  int bh = blockIdx.y;
  int s0 = blockIdx.x << 8;
  int t = threadIdx.x;
  int wave = t >> 6, lane = t & 63;
  __shared__ float qv[4][128];
  __shared__ float absq[128];
  __shared__ int sel[RANKN];
  __shared__ float qp[4][RANKN];
  __shared__ float wred[4][4];

  // zero out rows for this bh (poisoned 0xAA each call; k7 atomicAdds)
  if (blockIdx.x == 1) {
    out[(size_t)bh * 512 + t] = 0.f;
    out[(size_t)bh * 512 + 256 + t] = 0.f;
  }

  // ---- selection prep (replicated per block) ----
  {
    float v0 = q[(size_t)bh * 512 + t];
    float v1 = q[(size_t)bh * 512 + 256 + t];
    qv[t >> 7][t & 127] = v0;
    qv[2 + (t >> 7)][t & 127] = v1;
  }
  __syncthreads();
  if (t < 128)
    absq[t] = fabsf(qv[0][t]) + fabsf(qv[1][t]) + fabsf(qv[2][t]) + fabsf(qv[3][t]);
  __syncthreads();
  if (t < 128) {
    float a = absq[t];
    int rank = 0;
    for (int e = 0; e < 128; ++e) {
      float ae = absq[e];
      rank += (ae > a) || (ae == a && e < t);
    }
    if (rank < RANKN) sel[rank] = t;
  }
  __syncthreads();
  // per-p (wave==p) full |q| sum and selected |q| sum via shuffles
  {
    float fa = fabsf(qv[wave][lane]) + fabsf(qv[wave][lane + 64]);
    for (int off = 32; off > 0; off >>= 1) fa += __shfl_down(fa, off);
    float full = __shfl(fa, 0);
    float qsel = (lane < RANKN) ? qv[wave][sel[lane]] : 0.f;
    float sv = fabsf(qsel);
    for (int off = 32; off > 0; off >>= 1) sv += __shfl_down(sv, off);
    float selsum = __shfl(sv, 0);
    float scale = sqrtf(selsum / full * 128.f);
    if (lane < RANKN) qp[wave][lane] = qsel / scale;
  }
  __syncthreads();

  // current-token score (block x==0 only; wave == p)
  if (blockIdx.x == 0) {
    float kv = (lane < RANKN) ? key[bh * 128 + sel[lane]] : 0.f;
    float pr = (lane < RANKN) ? qp[wave][lane] * kv : 0.f;
    for (int off = 32; off > 0; off >>= 1) pr += __shfl_down(pr, off);
    if (lane == 0)
      scores[(size_t)(bh * 4 + wave) * SSTR + SEQKV] =
          pr + lm[(size_t)(bh * 4 + wave) * SEQN + SEQKV];
  }

  // ---- main approximate-score loop over this 256-position chunk ----
  const float* kb = skey + (size_t)bh * 128 * 4096;
  float a0 = 0, a1 = 0, a2 = 0, a3 = 0;
#pragma unroll 8
  for (int r = 0; r < RANKN; ++r) {
    float k0 = kb[((size_t)sel[r] << 12) + s0 + t];
    a0 += qp[0][r] * k0;
    a1 += qp[1][r] * k0;
    a2 += qp[2][r] * k0;
    a3 += qp[3][r] * k0;
  }
  float sc[4];
  {
    int s = s0 + t;
    sc[0] = a0 + lm[(size_t)(bh * 4 + 0) * SEQN + s];
    sc[1] = a1 + lm[(size_t)(bh * 4 + 1) * SEQN + s];
    sc[2] = a2 + lm[(size_t)(bh * 4 + 2) * SEQN + s];
    sc[3] = a3 + lm[(size_t)(bh * 4 + 3) * SEQN + s];
    float sum = sc[0] + sc[1] + sc[2] + sc[3];
#pragma unroll
    for (int p = 0; p < 4; ++p)
      scores[(size_t)(bh * 4 + p) * SSTR + s] = sc[p];
    tk[(bh << 12) + s] = sum;
  }

  // ---- per-chunk softmax partials (max, sum-exp) per p ----
#pragma unroll
  for (int p = 0; p < 4; ++p) {
    float mx = sc[p];
    for (int off = 32; off > 0; off >>= 1) mx = fmaxf(mx, __shfl_down(mx, off));
    if (lane == 0) wred[wave][p] = mx;
  }
  __syncthreads();
  float bm[4];
#pragma unroll
  for (int p = 0; p < 4; ++p)
    bm[p] = fmaxf(fmaxf(wred[0][p], wred[1][p]), fmaxf(wred[2][p], wred[3][p]));
  __syncthreads();  // wred reuse
#pragma unroll
  for (int p = 0; p < 4; ++p) {
    float e = expf(sc[p] - bm[p]);
    for (int off = 32; off > 0; off >>= 1) e += __shfl_down(e, off);
    if (lane == 0) wred[wave][p] = e;
  }
  __syncthreads();
  if (t < 4) {
    float s = wred[0][t] + wred[1][t] + wred[2][t] + wred[3][t];
    partials[(size_t)(bh * 4 + t) * NCHUNK + blockIdx.x] = make_float2(bm[t], s);
  }
}

// ---------------------------------------------------------------------------
// Kernel 3: top-384-of-3964 radix-select + hybrid register bitonic sort.
// Exact jax.lax.top_k(516) order: 132 masked (+inf) indices first
// (ascending), then the top-384 real sums descending, ties -> lower index.
// ---------------------------------------------------------------------------
__global__ __launch_bounds__(256) void k3_topk(
    const float* __restrict__ tk, int* __restrict__ indices) {
  int bh = blockIdx.x;
  int t = threadIdx.x;
  int lane = t & 63;
  __shared__ unsigned us[4096];               // sortable keys, 16 KB
  __shared__ unsigned hist[2048];             // 8 KB
  __shared__ unsigned long long binlist[2048];// 16 KB
  __shared__ unsigned long long selk[512];    // 4 KB
  __shared__ unsigned chunkSum[32];
  __shared__ int c1, c2, binB_s, nAbove_s, needed_s;

  {
    const float4* tk4 = (const float4*)(tk + (bh << 12));
    for (int i = t; i < 1024; i += 256) {
      float4 v = tk4[i];
      unsigned b0 = __float_as_uint(v.x), b1 = __float_as_uint(v.y);
      unsigned b2 = __float_as_uint(v.z), b3 = __float_as_uint(v.w);
      us[i * 4 + 0] = (b0 & 0x80000000u) ? ~b0 : (b0 | 0x80000000u);
      us[i * 4 + 1] = (b1 & 0x80000000u) ? ~b1 : (b1 | 0x80000000u);
      us[i * 4 + 2] = (b2 & 0x80000000u) ? ~b2 : (b2 | 0x80000000u);
      us[i * 4 + 3] = (b3 & 0x80000000u) ? ~b3 : (b3 | 0x80000000u);
    }
  }
  for (int i = t; i < 2048; i += 256) hist[i] = 0;
  if (t == 0) { c1 = 0; c2 = 0; }
  __syncthreads();

  // histogram of candidates s in [SINKN, SEQKV-LOCALK) on top 11 bits
  for (int s = SINKN + t; s < SEQKV - LOCALK; s += 256)
    atomicAdd(&hist[us[s] >> 21], 1u);
  __syncthreads();

  if (t < 32) {
    unsigned sum = 0;
    for (int i = 0; i < 64; ++i) sum += hist[t * 64 + i];
    chunkSum[t] = sum;
  }
  __syncthreads();

  if (t < 64) {
    int l = t;
    // suffix-inclusive sum over 32 chunk sums (higher chunk = larger keys)
    unsigned x = (l < 32) ? chunkSum[l] : 0;
    unsigned sfx = x;
    for (int off = 1; off < 64; off <<= 1) {
      unsigned y = __shfl_down(sfx, off);
      if (l + off < 64) sfx += y;
    }
    unsigned above = sfx - x;  // count in chunks strictly above mine
    bool hit = (l < 32) && (above < NTOP) && (above + x >= NTOP);
    unsigned long long mask = __ballot(hit);
    int C = __ffsll(mask) - 1;
    unsigned aboveC = __shfl(above, C);
    // refine within chunk C over its 64 bins
    unsigned h = hist[C * 64 + l];
    unsigned sfx2 = h;
    for (int off = 1; off < 64; off <<= 1) {
      unsigned y = __shfl_down(sfx2, off);
      if (l + off < 64) sfx2 += y;
    }
    unsigned above2 = aboveC + (sfx2 - h);
    bool hit2 = (above2 < NTOP) && (above2 + h >= NTOP);
    unsigned long long mask2 = __ballot(hit2);
    int lB = __ffsll(mask2) - 1;
    if (l == lB) {
      binB_s = C * 64 + l;
      nAbove_s = (int)above2;
      needed_s = NTOP - (int)above2;
    }
  }
  __syncthreads();
  unsigned B = (unsigned)binB_s;
  int nAbove = nAbove_s, needed = needed_s;

  // collect: definite winners -> selk, boundary-bin members -> binlist.
  // wave-aggregated compaction: one LDS atomic per wave per category.
  for (int s0 = SINKN; s0 < SEQKV - LOCALK; s0 += 256) {
    int s = s0 + t;
    bool valid = (s < SEQKV - LOCALK);
    unsigned u = valid ? us[s] : 0u;
    unsigned bin = u >> 21;
    bool win = valid && (bin > B);
    bool bnd = valid && (bin == B);
    unsigned long long mw = __ballot(win);
    unsigned long long mb = __ballot(bnd);
    int bw = 0, bb = 0;
    if (lane == 0) {
      if (mw) bw = atomicAdd(&c1, __popcll(mw));
      if (mb) bb = atomicAdd(&c2, __popcll(mb));
    }
    bw = __shfl(bw, 0);
    bb = __shfl(bb, 0);
    unsigned long long lmask = (1ULL << lane) - 1ULL;
    unsigned long long key = ((unsigned long long)u << 32) | (unsigned)(~s);
    if (win) selk[bw + __popcll(mw & lmask)] = key;
    if (bnd) {
      int pos = bb + __popcll(mb & lmask);
      if (pos < 2048) binlist[pos] = key;
    }
  }
  __syncthreads();
  int m2 = c2;
  int p2 = 1;
  while (p2 < m2) p2 <<= 1;
  for (int i = m2 + t; i < p2; i += 256) binlist[i] = 0ULL;
  __syncthreads();
  // bitonic sort (descending) of the boundary bin (small: ~hist[B] entries)
  for (int k = 2; k <= p2; k <<= 1)
    for (int j = k >> 1; j > 0; j >>= 1) {
      for (int i = t; i < p2; i += 256) {
        int ixj = i ^ j;
        if (ixj > i) {
          bool desc = ((i & k) == 0);
          unsigned long long a = binlist[i], bb2 = binlist[ixj];
          if ((a < bb2) == desc) { binlist[i] = bb2; binlist[ixj] = a; }
        }
      }
      __syncthreads();
    }
  for (int i = t; i < needed; i += 256) selk[nAbove + i] = binlist[i];
  for (int i = NTOP + t; i < 512; i += 256) selk[i] = 0ULL;
  __syncthreads();

  // hybrid register bitonic sort (descending) of 512:
  // thread t holds elements i0=t, i1=t+256. j=256 -> local swap,
  // j in {64,128} -> LDS exchange, j<64 -> shfl_xor in-wave.
  unsigned long long e0 = selk[t], e1 = selk[t + 256];
  int i1 = t + 256;
  for (int k = 2; k <= 512; k <<= 1) {
    for (int j = k >> 1; j > 0; j >>= 1) {
      if (j == 256) {
        if (e0 < e1) { unsigned long long tmp = e0; e0 = e1; e1 = tmp; }
      } else if (j >= 64) {
        selk[t] = e0; selk[i1] = e1;
        __syncthreads();
        unsigned long long p0 = selk[t ^ j], p1 = selk[i1 ^ j];
        __syncthreads();
        bool d0 = ((t & k) == 0), l0 = ((t & j) == 0);
        e0 = (d0 == l0) ? (e0 > p0 ? e0 : p0) : (e0 < p0 ? e0 : p0);
        bool d1 = ((i1 & k) == 0), l1 = ((i1 & j) == 0);
        e1 = (d1 == l1) ? (e1 > p1 ? e1 : p1) : (e1 < p1 ? e1 : p1);
      } else {
        unsigned long long p0 = __shfl_xor(e0, j);
        unsigned long long p1 = __shfl_xor(e1, j);
        bool d0 = ((t & k) == 0), l0 = ((t & j) == 0);
        e0 = (d0 == l0) ? (e0 > p0 ? e0 : p0) : (e0 < p0 ? e0 : p0);
        bool d1 = ((i1 & k) == 0);
        e1 = (d1 == l0) ? (e1 > p1 ? e1 : p1) : (e1 < p1 ? e1 : p1);
      }
    }
  }

  // emit: masked first (index-ascending), then top-384 descending
  if (t < SINKN) indices[bh * KSEL + t] = t;
  for (int i = t; i < LOCALK; i += 256)
    indices[bh * KSEL + SINKN + i] = (SEQKV - LOCALK) + i;
  indices[bh * KSEL + NMASK + t] = (int)(~(unsigned)(e0 & 0xFFFFFFFFu));
  if (t < NTOP - 256)
    indices[bh * KSEL + NMASK + 256 + t] = (int)(~(unsigned)(e1 & 0xFFFFFFFFu));
}

// ---------------------------------------------------------------------------
// Kernel 5: gathered QK^T scores. grid (26, 32 bh), block 256 = 4 waves.
// ---------------------------------------------------------------------------
__global__ __launch_bounds__(256) void k5_qk(
    const float* __restrict__ q, const float* __restrict__ key,
    const float* __restrict__ lm, const float* __restrict__ key_cpu,
    const int* __restrict__ indices, float* __restrict__ s2_g) {
  int bh = blockIdx.y;
  int t = threadIdx.x;
  int wave = t >> 6, lane = t & 63;
  __shared__ float qs[512];
  __shared__ int sidx[KSEL];
  qs[t] = q[((size_t)bh * 4 << 7) + t];
  qs[t + 256] = q[((size_t)bh * 4 << 7) + t + 256];
  for (int j = t; j < KSEL; j += 256) sidx[j] = indices[bh * KSEL + j];
  __syncthreads();

  const float rsqd = 0.08838834764831845f;  // 1/sqrt(128)
  float q0a = qs[lane * 2], q0b = qs[lane * 2 + 1];
  float q1a = qs[128 + lane * 2], q1b = qs[128 + lane * 2 + 1];
  float q2a = qs[256 + lane * 2], q2b = qs[256 + lane * 2 + 1];
  float q3a = qs[384 + lane * 2], q3b = qs[384 + lane * 2 + 1];

  for (int i = 0; i < 5; ++i) {
    int j = (blockIdx.x << 2) + wave + 104 * i;
    if (j > KSEL) continue;
    int sj = (j < KSEL) ? sidx[j] : SEQKV;
    const float* krow = (j < KSEL)
        ? key_cpu + ((((size_t)bh << 12) + sj) << 7)
        : key + ((size_t)bh << 7);
    float2 kk = ((const float2*)krow)[lane];
    float p0 = q0a * kk.x + q0b * kk.y;
    float p1 = q1a * kk.x + q1b * kk.y;
    float p2 = q2a * kk.x + q2b * kk.y;
    float p3 = q3a * kk.x + q3b * kk.y;
    for (int off = 32; off > 0; off >>= 1) {
      p0 += __shfl_down(p0, off);
      p1 += __shfl_down(p1, off);
      p2 += __shfl_down(p2, off);
      p3 += __shfl_down(p3, off);
    }
    if (lane == 0) {
      size_t lmb = (size_t)bh * 4 * SEQN + sj;
      s2_g[(bh * 4 + 0) * 520 + j] = p0 * rsqd + lm[lmb + 0 * SEQN];
      s2_g[(bh * 4 + 1) * 520 + j] = p1 * rsqd + lm[lmb + 1 * SEQN];
      s2_g[(bh * 4 + 2) * 520 + j] = p2 * rsqd + lm[lmb + 2 * SEQN];
      s2_g[(bh * 4 + 3) * 520 + j] = p3 * rsqd + lm[lmb + 3 * SEQN];
    }
  }
}

// ---------------------------------------------------------------------------
// Kernel 7 (fused k6+k7): per block (chunk c, bh):
//   wave w recomputes softmax stats for p=w (partial-merge -> kvw via
//   516-gather; m2/se2 over the 517 gathered scores) with shuffle
//   reductions; block then computes its chunk's 32x4 weights, writes out_w,
//   and accumulates w*V into out (atomicAdd; out zeroed by k2).
//   Chunk-0 blocks also add the (1-kvw)*mean_v_new term.
// grid (17, 32 bh), block 256.
// ---------------------------------------------------------------------------
__global__ __launch_bounds__(256) void k7_wv(
    const float* __restrict__ value, const float* __restrict__ value_cpu,
    const float* __restrict__ mean_v, const int* __restrict__ indices,
    const float* __restrict__ s2_g, const float* __restrict__ scores,
    const float2* __restrict__ partials,
    float* __restrict__ out_w, float* __restrict__ out) {
  int bh = blockIdx.y;
  int c0 = blockIdx.x << 5;  // chunk start j
  int t = threadIdx.x;
  int wave = t >> 6, lane = t & 63;
  int d = t & 127, half = t >> 7;
  __shared__ int sidx[KSEL];
  __shared__ float wsh[4][32];
  __shared__ float kvw_s[4], m2_s[4], inv_s[4];
  __shared__ float red[2][4][128];

  for (int j = t; j < KSEL; j += 256) sidx[j] = indices[bh * KSEL + j];
  __syncthreads();

  // ---- per-wave (p = wave) softmax stats ----
  {
    int p = wave;
    const float* srow = scores + (size_t)(bh * 4 + p) * SSTR;
    const float* s2r = s2_g + (size_t)(bh * 4 + p) * 520;
    float cur = srow[SEQKV];
    // merge k2's per-chunk partials (uniform across the wave)
    float m = cur;
    float2 pc[NCHUNK];
#pragma unroll
    for (int c = 0; c < NCHUNK; ++c) {
      pc[c] = partials[(size_t)(bh * 4 + p) * NCHUNK + c];
      m = fmaxf(m, pc[c].x);
    }
    float sumexp = expf(cur - m);
#pragma unroll
    for (int c = 0; c < NCHUNK; ++c) sumexp += pc[c].y * expf(pc[c].x - m);
    // selected mass over the 516 gathered positions
    float ss = 0.f;
    for (int j = lane; j < KSEL; j += 64) ss += expf(srow[sidx[j]] - m);
    for (int off = 32; off > 0; off >>= 1) ss += __shfl_down(ss, off);
    ss = __shfl(ss, 0);
    float kvw = (ss + expf(cur - m)) / sumexp;
    // softmax stats over the 517 gathered scores
    float mx2 = -INFINITY;
    for (int j = lane; j < KSEL + 1; j += 64) mx2 = fmaxf(mx2, s2r[j]);
    for (int off = 32; off > 0; off >>= 1) mx2 = fmaxf(mx2, __shfl_down(mx2, off));
    mx2 = __shfl(mx2, 0);
    float se2 = 0.f;
    for (int j = lane; j < KSEL + 1; j += 64) se2 += expf(s2r[j] - mx2);
    for (int off = 32; off > 0; off >>= 1) se2 += __shfl_down(se2, off);
    se2 = __shfl(se2, 0);
    if (lane == 0) {
      kvw_s[p] = kvw;
      m2_s[p] = mx2;
      inv_s[p] = kvw / se2;
    }
  }
  __syncthreads();

  // ---- this chunk's weights + out_w ----
  int nj = min(32, KSEL + 1 - c0);
  if (t < 128) {
    int p = t >> 5, jl = t & 31;
    float w = 0.f;
    if (jl < nj) {
      int j = c0 + jl;
      w = expf(s2_g[(size_t)(bh * 4 + p) * 520 + j] - m2_s[p]) * inv_s[p];
      out_w[(size_t)(bh * 4 + p) * (KSEL + 1) + j] = w;
    }
    wsh[p][jl] = w;
  }
  __syncthreads();

  // ---- w * V accumulation ----
  float a0 = 0, a1 = 0, a2 = 0, a3 = 0;
  for (int jl = half; jl < nj; jl += 2) {
    int j = c0 + jl;
    const float* vrow = (j < KSEL)
        ? value_cpu + ((((size_t)bh << 12) + sidx[j]) << 7)
        : value + ((size_t)bh << 7);
    float v = vrow[d];
    a0 += wsh[0][jl] * v;
    a1 += wsh[1][jl] * v;
    a2 += wsh[2][jl] * v;
    a3 += wsh[3][jl] * v;
  }
  red[half][0][d] = a0; red[half][1][d] = a1;
  red[half][2][d] = a2; red[half][3][d] = a3;
  __syncthreads();
  if (half == 0) {
#pragma unroll
    for (int p = 0; p < 4; ++p) {
      float s = red[0][p][d] + red[1][p][d];
      atomicAdd(&out[(size_t)(bh * 4 + p) * 128 + d], s);
    }
  }

  // ---- mean_v term (chunk-0 blocks only) ----
  if (blockIdx.x == 0 && t < 128) {
    float vcur = value[((size_t)bh << 7) + t];
    float mvn = (mean_v[((size_t)bh << 7) + t] * 4096.f + vcur) / 4097.f;
#pragma unroll
    for (int p = 0; p < 4; ++p)
      atomicAdd(&out[(size_t)(bh * 4 + p) * 128 + t], (1.f - kvw_s[p]) * mvn);
  }
}

// ---------------------------------------------------------------------------
extern "C" void kernel_launch(void* const* d_in, const int* in_sizes, int n_in,
                              void* d_out, int out_size, void* d_ws, size_t ws_size,
                              hipStream_t stream) {
  const float* query     = (const float*)d_in[0];
  const float* key       = (const float*)d_in[1];
  const float* value     = (const float*)d_in[2];
  const float* logmask   = (const float*)d_in[3];
  const float* key_cpu   = (const float*)d_in[4];
  const float* value_cpu = (const float*)d_in[5];
  const float* s_key_cpu = (const float*)d_in[6];
  const float* mean_v    = (const float*)d_in[7];

  float* out   = (float*)d_out;       // (4,32,1,128) = 16384 floats
  float* out_w = out + 16384;         // (4,32,1,517) = 66176 floats

  char* ws = (char*)d_ws;
  int*    indices  = (int*)(ws + 20480);          // 66048 B
  float*  scores   = (float*)(ws + 86528);        // 128*4100*4 = 2099200 B
  float*  tk       = (float*)(ws + 2185728);      // 524288 B
  float*  s2_g     = (float*)(ws + 2710016);      // 266240 B
  float2* partials = (float2*)(ws + 2976256);     // 128*16*8 = 16384 B
  // total ws use: 2,992,640 bytes

  hipLaunchKernelGGL(k2_scores, dim3(NCHUNK, NBH), dim3(256), 0, stream,
                     query, key, s_key_cpu, logmask, scores, tk, partials, out);
  hipLaunchKernelGGL(k3_topk, dim3(NBH), dim3(256), 0, stream,
                     tk, indices);
  hipLaunchKernelGGL(k5_qk, dim3(26, NBH), dim3(256), 0, stream,
                     query, key, logmask, key_cpu, indices, s2_g);
  hipLaunchKernelGGL(k7_wv, dim3(17, NBH), dim3(256), 0, stream,
                     value, value_cpu, mean_v, indices, s2_g, scores,
                     partials, out_w, out);
}

// Round 8
// 230.630 us; speedup vs baseline: 1.0079x; 1.0079x over previous
//
#include <hip/hip_runtime.h>
#include <hip/hip_bf16.h>
#include <math.h>

// Problem constants
#define NBH 32     // B*KVH = 4*8
#define HPKN 4
#define DN 128
#define SEQKV 4096
#define SEQN 4097
#define SSTR 4100  // padded score-row stride (keeps float4 alignment per row)
#define RANKN 32
#define KSEL 516   // K + SINK = 512 + 4
#define SINKN 4
#define LOCALK 128 // masked-local region starts at SEQKV - LOCALK = 3968
#define NMASK 132  // SINKN + LOCALK
#define NTOP 384   // KSEL - NMASK
#define NCHUNK 16  // k2 position-chunks per bh

// ---------------------------------------------------------------------------
// Kernel 2: per block, recompute rank-32 dim selection + scales from q via
// shuffle reductions, then approximate scores over this block's 256-position
// chunk. Emits per-chunk softmax partials (max, sum-exp) per (bh,p).
// Block x==0 also writes the current-token (s=4096) score.
// grid (16, 32 bh), block 256.
// ---------------------------------------------------------------------------
__global__ __launch_bounds__(256) void k2_scores(
    const float* __restrict__ q, const float* __restrict__ key,
    const float* __restrict__ skey, const float* __restrict__ lm,
    float* __restrict__ scores, float* __restrict__ tk,
    float2* __restrict__ partials) {
  int bh = blockIdx.y;
  int s0 = blockIdx.x << 8;
  int t = threadIdx.x;
  int wave = t >> 6, lane = t & 63;
  __shared__ float qv[4][128];
  __shared__ float absq[128];
  __shared__ int sel[RANKN];
  __shared__ float qp[4][RANKN];
  __shared__ float wred[4][4];

  // ---- selection prep (replicated per block) ----
  {
    float v0 = q[(size_t)bh * 512 + t];
    float v1 = q[(size_t)bh * 512 + 256 + t];
    qv[t >> 7][t & 127] = v0;
    qv[2 + (t >> 7)][t & 127] = v1;
  }
  __syncthreads();
  if (t < 128)
    absq[t] = fabsf(qv[0][t]) + fabsf(qv[1][t]) + fabsf(qv[2][t]) + fabsf(qv[3][t]);
  __syncthreads();
  if (t < 128) {
    float a = absq[t];
    int rank = 0;
    for (int e = 0; e < 128; ++e) {
      float ae = absq[e];
      rank += (ae > a) || (ae == a && e < t);
    }
    if (rank < RANKN) sel[rank] = t;
  }
  __syncthreads();
  // per-p (wave==p) full |q| sum and selected |q| sum via shuffles
  {
    float fa = fabsf(qv[wave][lane]) + fabsf(qv[wave][lane + 64]);
    for (int off = 32; off > 0; off >>= 1) fa += __shfl_down(fa, off);
    float full = __shfl(fa, 0);
    float qsel = (lane < RANKN) ? qv[wave][sel[lane]] : 0.f;
    float sv = fabsf(qsel);
    for (int off = 32; off > 0; off >>= 1) sv += __shfl_down(sv, off);
    float selsum = __shfl(sv, 0);
    float scale = sqrtf(selsum / full * 128.f);
    if (lane < RANKN) qp[wave][lane] = qsel / scale;
  }
  __syncthreads();

  // current-token score (block x==0 only; wave == p)
  if (blockIdx.x == 0) {
    float kv = (lane < RANKN) ? key[bh * 128 + sel[lane]] : 0.f;
    float pr = (lane < RANKN) ? qp[wave][lane] * kv : 0.f;
    for (int off = 32; off > 0; off >>= 1) pr += __shfl_down(pr, off);
    if (lane == 0)
      scores[(size_t)(bh * 4 + wave) * SSTR + SEQKV] =
          pr + lm[(size_t)(bh * 4 + wave) * SEQN + SEQKV];
  }

  // ---- main approximate-score loop over this 256-position chunk ----
  const float* kb = skey + (size_t)bh * 128 * 4096;
  float a0 = 0, a1 = 0, a2 = 0, a3 = 0;
#pragma unroll 8
  for (int r = 0; r < RANKN; ++r) {
    float k0 = kb[((size_t)sel[r] << 12) + s0 + t];
    a0 += qp[0][r] * k0;
    a1 += qp[1][r] * k0;
    a2 += qp[2][r] * k0;
    a3 += qp[3][r] * k0;
  }
  float sc[4];
  {
    int s = s0 + t;
    sc[0] = a0 + lm[(size_t)(bh * 4 + 0) * SEQN + s];
    sc[1] = a1 + lm[(size_t)(bh * 4 + 1) * SEQN + s];
    sc[2] = a2 + lm[(size_t)(bh * 4 + 2) * SEQN + s];
    sc[3] = a3 + lm[(size_t)(bh * 4 + 3) * SEQN + s];
    float sum = sc[0] + sc[1] + sc[2] + sc[3];
#pragma unroll
    for (int p = 0; p < 4; ++p)
      scores[(size_t)(bh * 4 + p) * SSTR + s] = sc[p];
    tk[(bh << 12) + s] = sum;
  }

  // ---- per-chunk softmax partials (max, sum-exp) per p ----
#pragma unroll
  for (int p = 0; p < 4; ++p) {
    float mx = sc[p];
    for (int off = 32; off > 0; off >>= 1) mx = fmaxf(mx, __shfl_down(mx, off));
    if (lane == 0) wred[wave][p] = mx;
  }
  __syncthreads();
  float bm[4];
#pragma unroll
  for (int p = 0; p < 4; ++p)
    bm[p] = fmaxf(fmaxf(wred[0][p], wred[1][p]), fmaxf(wred[2][p], wred[3][p]));
  __syncthreads();  // wred reuse
#pragma unroll
  for (int p = 0; p < 4; ++p) {
    float e = expf(sc[p] - bm[p]);
    for (int off = 32; off > 0; off >>= 1) e += __shfl_down(e, off);
    if (lane == 0) wred[wave][p] = e;
  }
  __syncthreads();
  if (t < 4) {
    float s = wred[0][t] + wred[1][t] + wred[2][t] + wred[3][t];
    partials[(size_t)(bh * 4 + t) * NCHUNK + blockIdx.x] = make_float2(bm[t], s);
  }
}

// ---------------------------------------------------------------------------
// Kernel 3: top-384-of-3964 radix-select + hybrid register bitonic sort.
// Exact jax.lax.top_k(516) order: 132 masked (+inf) indices first
// (ascending), then the top-384 real sums descending, ties -> lower index.
// ---------------------------------------------------------------------------
__global__ __launch_bounds__(256) void k3_topk(
    const float* __restrict__ tk, int* __restrict__ indices) {
  int bh = blockIdx.x;
  int t = threadIdx.x;
  int lane = t & 63;
  __shared__ unsigned us[4096];               // sortable keys, 16 KB
  __shared__ unsigned hist[2048];             // 8 KB
  __shared__ unsigned long long binlist[2048];// 16 KB
  __shared__ unsigned long long selk[512];    // 4 KB
  __shared__ unsigned chunkSum[32];
  __shared__ int c1, c2, binB_s, nAbove_s, needed_s;

  {
    const float4* tk4 = (const float4*)(tk + (bh << 12));
    for (int i = t; i < 1024; i += 256) {
      float4 v = tk4[i];
      unsigned b0 = __float_as_uint(v.x), b1 = __float_as_uint(v.y);
      unsigned b2 = __float_as_uint(v.z), b3 = __float_as_uint(v.w);
      us[i * 4 + 0] = (b0 & 0x80000000u) ? ~b0 : (b0 | 0x80000000u);
      us[i * 4 + 1] = (b1 & 0x80000000u) ? ~b1 : (b1 | 0x80000000u);
      us[i * 4 + 2] = (b2 & 0x80000000u) ? ~b2 : (b2 | 0x80000000u);
      us[i * 4 + 3] = (b3 & 0x80000000u) ? ~b3 : (b3 | 0x80000000u);
    }
  }
  for (int i = t; i < 2048; i += 256) hist[i] = 0;
  if (t == 0) { c1 = 0; c2 = 0; }
  __syncthreads();

  // histogram of candidates s in [SINKN, SEQKV-LOCALK) on top 11 bits
  for (int s = SINKN + t; s < SEQKV - LOCALK; s += 256)
    atomicAdd(&hist[us[s] >> 21], 1u);
  __syncthreads();

  if (t < 32) {
    unsigned sum = 0;
    for (int i = 0; i < 64; ++i) sum += hist[t * 64 + i];
    chunkSum[t] = sum;
  }
  __syncthreads();

  if (t < 64) {
    int l = t;
    // suffix-inclusive sum over 32 chunk sums (higher chunk = larger keys)
    unsigned x = (l < 32) ? chunkSum[l] : 0;
    unsigned sfx = x;
    for (int off = 1; off < 64; off <<= 1) {
      unsigned y = __shfl_down(sfx, off);
      if (l + off < 64) sfx += y;
    }
    unsigned above = sfx - x;  // count in chunks strictly above mine
    bool hit = (l < 32) && (above < NTOP) && (above + x >= NTOP);
    unsigned long long mask = __ballot(hit);
    int C = __ffsll(mask) - 1;
    unsigned aboveC = __shfl(above, C);
    // refine within chunk C over its 64 bins
    unsigned h = hist[C * 64 + l];
    unsigned sfx2 = h;
    for (int off = 1; off < 64; off <<= 1) {
      unsigned y = __shfl_down(sfx2, off);
      if (l + off < 64) sfx2 += y;
    }
    unsigned above2 = aboveC + (sfx2 - h);
    bool hit2 = (above2 < NTOP) && (above2 + h >= NTOP);
    unsigned long long mask2 = __ballot(hit2);
    int lB = __ffsll(mask2) - 1;
    if (l == lB) {
      binB_s = C * 64 + l;
      nAbove_s = (int)above2;
      needed_s = NTOP - (int)above2;
    }
  }
  __syncthreads();
  unsigned B = (unsigned)binB_s;
  int nAbove = nAbove_s, needed = needed_s;

  // collect: definite winners -> selk, boundary-bin members -> binlist.
  // wave-aggregated compaction: one LDS atomic per wave per category.
  for (int s0 = SINKN; s0 < SEQKV - LOCALK; s0 += 256) {
    int s = s0 + t;
    bool valid = (s < SEQKV - LOCALK);
    unsigned u = valid ? us[s] : 0u;
    unsigned bin = u >> 21;
    bool win = valid && (bin > B);
    bool bnd = valid && (bin == B);
    unsigned long long mw = __ballot(win);
    unsigned long long mb = __ballot(bnd);
    int bw = 0, bb = 0;
    if (lane == 0) {
      if (mw) bw = atomicAdd(&c1, __popcll(mw));
      if (mb) bb = atomicAdd(&c2, __popcll(mb));
    }
    bw = __shfl(bw, 0);
    bb = __shfl(bb, 0);
    unsigned long long lmask = (1ULL << lane) - 1ULL;
    unsigned long long key = ((unsigned long long)u << 32) | (unsigned)(~s);
    if (win) selk[bw + __popcll(mw & lmask)] = key;
    if (bnd) {
      int pos = bb + __popcll(mb & lmask);
      if (pos < 2048) binlist[pos] = key;
    }
  }
  __syncthreads();
  int m2 = c2;
  int p2 = 1;
  while (p2 < m2) p2 <<= 1;
  for (int i = m2 + t; i < p2; i += 256) binlist[i] = 0ULL;
  __syncthreads();
  // bitonic sort (descending) of the boundary bin (small: ~hist[B] entries)
  for (int k = 2; k <= p2; k <<= 1)
    for (int j = k >> 1; j > 0; j >>= 1) {
      for (int i = t; i < p2; i += 256) {
        int ixj = i ^ j;
        if (ixj > i) {
          bool desc = ((i & k) == 0);
          unsigned long long a = binlist[i], bb2 = binlist[ixj];
          if ((a < bb2) == desc) { binlist[i] = bb2; binlist[ixj] = a; }
        }
      }
      __syncthreads();
    }
  for (int i = t; i < needed; i += 256) selk[nAbove + i] = binlist[i];
  for (int i = NTOP + t; i < 512; i += 256) selk[i] = 0ULL;
  __syncthreads();

  // hybrid register bitonic sort (descending) of 512:
  // thread t holds elements i0=t, i1=t+256. j=256 -> local swap,
  // j in {64,128} -> LDS exchange, j<64 -> shfl_xor in-wave.
  unsigned long long e0 = selk[t], e1 = selk[t + 256];
  int i1 = t + 256;
  for (int k = 2; k <= 512; k <<= 1) {
    for (int j = k >> 1; j > 0; j >>= 1) {
      if (j == 256) {
        if (e0 < e1) { unsigned long long tmp = e0; e0 = e1; e1 = tmp; }
      } else if (j >= 64) {
        selk[t] = e0; selk[i1] = e1;
        __syncthreads();
        unsigned long long p0 = selk[t ^ j], p1 = selk[i1 ^ j];
        __syncthreads();
        bool d0 = ((t & k) == 0), l0 = ((t & j) == 0);
        e0 = (d0 == l0) ? (e0 > p0 ? e0 : p0) : (e0 < p0 ? e0 : p0);
        bool d1 = ((i1 & k) == 0), l1 = ((i1 & j) == 0);
        e1 = (d1 == l1) ? (e1 > p1 ? e1 : p1) : (e1 < p1 ? e1 : p1);
      } else {
        unsigned long long p0 = __shfl_xor(e0, j);
        unsigned long long p1 = __shfl_xor(e1, j);
        bool d0 = ((t & k) == 0), l0 = ((t & j) == 0);
        e0 = (d0 == l0) ? (e0 > p0 ? e0 : p0) : (e0 < p0 ? e0 : p0);
        bool d1 = ((i1 & k) == 0);
        e1 = (d1 == l0) ? (e1 > p1 ? e1 : p1) : (e1 < p1 ? e1 : p1);
      }
    }
  }

  // emit: masked first (index-ascending), then top-384 descending
  if (t < SINKN) indices[bh * KSEL + t] = t;
  for (int i = t; i < LOCALK; i += 256)
    indices[bh * KSEL + SINKN + i] = (SEQKV - LOCALK) + i;
  indices[bh * KSEL + NMASK + t] = (int)(~(unsigned)(e0 & 0xFFFFFFFFu));
  if (t < NTOP - 256)
    indices[bh * KSEL + NMASK + 256 + t] = (int)(~(unsigned)(e1 & 0xFFFFFFFFu));
}

// ---------------------------------------------------------------------------
// Kernel 5: gathered QK^T scores. grid (26, 32 bh), block 256 = 4 waves.
// Per-wave index loaded directly from global (wave-uniform) — no 516-entry
// LDS staging (each block only uses ~20 of them).
// ---------------------------------------------------------------------------
__global__ __launch_bounds__(256) void k5_qk(
    const float* __restrict__ q, const float* __restrict__ key,
    const float* __restrict__ lm, const float* __restrict__ key_cpu,
    const int* __restrict__ indices, float* __restrict__ s2_g) {
  int bh = blockIdx.y;
  int t = threadIdx.x;
  int wave = t >> 6, lane = t & 63;
  __shared__ float qs[512];
  qs[t] = q[((size_t)bh * 4 << 7) + t];
  qs[t + 256] = q[((size_t)bh * 4 << 7) + t + 256];
  __syncthreads();

  const float rsqd = 0.08838834764831845f;  // 1/sqrt(128)
  float q0a = qs[lane * 2], q0b = qs[lane * 2 + 1];
  float q1a = qs[128 + lane * 2], q1b = qs[128 + lane * 2 + 1];
  float q2a = qs[256 + lane * 2], q2b = qs[256 + lane * 2 + 1];
  float q3a = qs[384 + lane * 2], q3b = qs[384 + lane * 2 + 1];

  for (int i = 0; i < 5; ++i) {
    int j = (blockIdx.x << 2) + wave + 104 * i;
    if (j > KSEL) continue;
    int sj = (j < KSEL) ? indices[bh * KSEL + j] : SEQKV;
    const float* krow = (j < KSEL)
        ? key_cpu + ((((size_t)bh << 12) + sj) << 7)
        : key + ((size_t)bh << 7);
    float2 kk = ((const float2*)krow)[lane];
    float p0 = q0a * kk.x + q0b * kk.y;
    float p1 = q1a * kk.x + q1b * kk.y;
    float p2 = q2a * kk.x + q2b * kk.y;
    float p3 = q3a * kk.x + q3b * kk.y;
    for (int off = 32; off > 0; off >>= 1) {
      p0 += __shfl_down(p0, off);
      p1 += __shfl_down(p1, off);
      p2 += __shfl_down(p2, off);
      p3 += __shfl_down(p3, off);
    }
    if (lane == 0) {
      size_t lmb = (size_t)bh * 4 * SEQN + sj;
      s2_g[(bh * 4 + 0) * 520 + j] = p0 * rsqd + lm[lmb + 0 * SEQN];
      s2_g[(bh * 4 + 1) * 520 + j] = p1 * rsqd + lm[lmb + 1 * SEQN];
      s2_g[(bh * 4 + 2) * 520 + j] = p2 * rsqd + lm[lmb + 2 * SEQN];
      s2_g[(bh * 4 + 3) * 520 + j] = p3 * rsqd + lm[lmb + 3 * SEQN];
    }
  }
}

// ---------------------------------------------------------------------------
// Kernel 6: per (bh,p): merge k2's softmax partials -> kv_weight (with the
// selected-mass gather); softmax over the 517 gathered scores; writes out_w,
// w_g, and initializes out with the (1-kvw)*mean_v_new term.
// grid 128, block 256.
// ---------------------------------------------------------------------------
__global__ __launch_bounds__(256) void k6_stats(
    const float* __restrict__ scores, const float2* __restrict__ partials,
    const int* __restrict__ indices, const float* __restrict__ s2_g,
    const float* __restrict__ value, const float* __restrict__ mean_v,
    float* __restrict__ out_w, float* __restrict__ w_g,
    float* __restrict__ out) {
  int bhp = blockIdx.x;
  int bh = bhp >> 2;
  int t = threadIdx.x;
  __shared__ int sidx[KSEL];
  __shared__ float red[256];
  __shared__ float bc;

  for (int j = t; j < KSEL; j += 256) sidx[j] = indices[bh * KSEL + j];
  __syncthreads();

  const float* srow = scores + (size_t)bhp * SSTR;
  float cur = srow[SEQKV];

  // merge the 16 per-chunk partials (uniform loads, all threads)
  float m = cur, sumexp;
  {
    float2 pc[NCHUNK];
#pragma unroll
    for (int c = 0; c < NCHUNK; ++c) {
      pc[c] = partials[(size_t)bhp * NCHUNK + c];
      m = fmaxf(m, pc[c].x);
    }
    float s = expf(cur - m);
#pragma unroll
    for (int c = 0; c < NCHUNK; ++c) s += pc[c].y * expf(pc[c].x - m);
    sumexp = s;
  }

  // selected mass (gather over the 516 selected positions)
  float ss = 0.f;
  for (int j = t; j < KSEL; j += 256) ss += expf(srow[sidx[j]] - m);
  red[t] = ss; __syncthreads();
  for (int st = 128; st > 0; st >>= 1) {
    if (t < st) red[t] += red[t + st];
    __syncthreads();
  }
  float kvw;
  if (t == 0) bc = (red[0] + expf(cur - m)) / sumexp;
  __syncthreads();
  kvw = bc; __syncthreads();

  // softmax over 517 gathered scores
  const float* s2r = s2_g + (size_t)bhp * 520;
  float mx2 = -INFINITY;
  for (int j = t; j < KSEL + 1; j += 256) mx2 = fmaxf(mx2, s2r[j]);
  red[t] = mx2; __syncthreads();
  for (int st = 128; st > 0; st >>= 1) {
    if (t < st) red[t] = fmaxf(red[t], red[t + st]);
    __syncthreads();
  }
  float m2 = red[0]; __syncthreads();
  float se2 = 0.f;
  for (int j = t; j < KSEL + 1; j += 256) se2 += expf(s2r[j] - m2);
  red[t] = se2; __syncthreads();
  for (int st = 128; st > 0; st >>= 1) {
    if (t < st) red[t] += red[t + st];
    __syncthreads();
  }
  float inv = kvw / red[0];

  for (int j = t; j < KSEL + 1; j += 256) {
    float w = expf(s2r[j] - m2) * inv;
    out_w[(size_t)bhp * (KSEL + 1) + j] = w;
    w_g[(size_t)bhp * 520 + j] = w;
  }

  // initialize out with (1-kvw) * mean_v_new
  if (t < 128) {
    float vcur = value[((size_t)bh << 7) + t];
    float mvn = (mean_v[((size_t)bh << 7) + t] * 4096.f + vcur) / 4097.f;
    out[((size_t)bhp << 7) + t] = (1.f - kvw) * mvn;
  }
}

// ---------------------------------------------------------------------------
// Kernel 7: out += sum_j w[p][j] * V_g[j][:]. grid (17, 32 bh), block 256
// (2 j-lanes x 128 d), 32 j per chunk. atomicAdd accumulation into out.
// ---------------------------------------------------------------------------
__global__ __launch_bounds__(256) void k7_wv(
    const float* __restrict__ value, const float* __restrict__ value_cpu,
    const int* __restrict__ indices, const float* __restrict__ w_g,
    float* __restrict__ out) {
  int bh = blockIdx.y;
  int c0 = blockIdx.x << 5;  // chunk start j
  int t = threadIdx.x;
  int d = t & 127, half = t >> 7;
  __shared__ int sidx[32];
  __shared__ float wsh[4][32];
  __shared__ float red[2][4][128];

  int nj = min(32, KSEL + 1 - c0);
  if (t < nj) {
    int j = c0 + t;
    sidx[t] = (j < KSEL) ? indices[bh * KSEL + j] : -1;
  }
  if (t < 128) {
    int p = t >> 5, jl = t & 31;
    wsh[p][jl] = (jl < nj) ? w_g[(size_t)(bh * 4 + p) * 520 + c0 + jl] : 0.f;
  }
  __syncthreads();

  float a0 = 0, a1 = 0, a2 = 0, a3 = 0;
  for (int jl = half; jl < nj; jl += 2) {
    int sj = sidx[jl];
    const float* vrow = (sj >= 0)
        ? value_cpu + ((((size_t)bh << 12) + sj) << 7)
        : value + ((size_t)bh << 7);
    float v = vrow[d];
    a0 += wsh[0][jl] * v;
    a1 += wsh[1][jl] * v;
    a2 += wsh[2][jl] * v;
    a3 += wsh[3][jl] * v;
  }
  red[half][0][d] = a0; red[half][1][d] = a1;
  red[half][2][d] = a2; red[half][3][d] = a3;
  __syncthreads();
  if (half == 0) {
#pragma unroll
    for (int p = 0; p < 4; ++p) {
      float s = red[0][p][d] + red[1][p][d];
      atomicAdd(&out[(size_t)(bh * 4 + p) * 128 + d], s);
    }
  }
}

// ---------------------------------------------------------------------------
extern "C" void kernel_launch(void* const* d_in, const int* in_sizes, int n_in,
                              void* d_out, int out_size, void* d_ws, size_t ws_size,
                              hipStream_t stream) {
  const float* query     = (const float*)d_in[0];
  const float* key       = (const float*)d_in[1];
  const float* value     = (const float*)d_in[2];
  const float* logmask   = (const float*)d_in[3];
  const float* key_cpu   = (const float*)d_in[4];
  const float* value_cpu = (const float*)d_in[5];
  const float* s_key_cpu = (const float*)d_in[6];
  const float* mean_v    = (const float*)d_in[7];

  float* out   = (float*)d_out;       // (4,32,1,128) = 16384 floats
  float* out_w = out + 16384;         // (4,32,1,517) = 66176 floats

  char* ws = (char*)d_ws;
  int*    indices  = (int*)(ws + 20480);          // 66048 B
  float*  scores   = (float*)(ws + 86528);        // 128*4100*4 = 2099200 B
  float*  tk       = (float*)(ws + 2185728);      // 524288 B
  float*  s2_g     = (float*)(ws + 2710016);      // 266240 B
  float*  w_g      = (float*)(ws + 2976256);      // 266240 B
  float2* partials = (float2*)(ws + 3242496);     // 128*16*8 = 16384 B
  // total ws use: 3,258,880 bytes

  hipLaunchKernelGGL(k2_scores, dim3(NCHUNK, NBH), dim3(256), 0, stream,
                     query, key, s_key_cpu, logmask, scores, tk, partials);
  hipLaunchKernelGGL(k3_topk, dim3(NBH), dim3(256), 0, stream,
                     tk, indices);
  hipLaunchKernelGGL(k5_qk, dim3(26, NBH), dim3(256), 0, stream,
                     query, key, logmask, key_cpu, indices, s2_g);
  hipLaunchKernelGGL(k6_stats, dim3(128), dim3(256), 0, stream,
                     scores, partials, indices, s2_g, value, mean_v,
                     out_w, w_g, out);
  hipLaunchKernelGGL(k7_wv, dim3(17, NBH), dim3(256), 0, stream,
                     value, value_cpu, indices, w_g, out);
}